// Round 4
// baseline (261.601 us; speedup 1.0000x reference)
//
#include <hip/hip_runtime.h>

#define B_  4
#define N_  4096
#define H_  16
#define D_  64
#define BH_ 64
#define S_  16
#define HS_ 4
#define EPS_ 1e-6f

typedef _Float16 h2  __attribute__((ext_vector_type(2)));
typedef float    f4v __attribute__((ext_vector_type(4)));

struct H2x4 { h2 e[4]; };
struct H2x2 { h2 a, b; };

__device__ __forceinline__ H2x4 ld_h2x4(const h2* p) {
    f4v r = *(const f4v*)p;                 // ds_read_b128
    return __builtin_bit_cast(H2x4, r);
}
__device__ __forceinline__ void st_h2x2(h2* p, h2 a, h2 b) {
    H2x2 t{a, b};
    *(float2*)p = __builtin_bit_cast(float2, t);   // ds_write_b64
}

__device__ __forceinline__ float phi(float x) {
    // elu(x)+1 : x>0 -> x+1 ; x<=0 -> exp(x)
    return x > 0.0f ? x + 1.0f : __expf(x);
}
__device__ __forceinline__ h2 phi2(float x, float y) {
    h2 r; r.x = (_Float16)phi(x); r.y = (_Float16)phi(y); return r;
}

__device__ __forceinline__ float fdot2(h2 a, h2 b, float c) {
    return __builtin_amdgcn_fdot2(a, b, c, false);
}

// ---------------------------------------------------------------------------
// Kernel 1a: partial KV[d][m] = sum_n phi(K[n,d]) * V[n,m], partial Ksum.
// grid (64 bh, 16 s), 256 threads (4 waves). Register-prefetch + LDS double
// buffer: chunk c+1's global loads are issued before compute of chunk c.
// Each wave computes the full 64x64 tile (8x8/lane) over its 16 n-rows;
// wave partials tree-reduced through LDS at block end.
// ---------------------------------------------------------------------------
__global__ __launch_bounds__(256) void k_kvpart(const float* __restrict__ K,
                                                const float* __restrict__ V,
                                                float* __restrict__ kvpart,
                                                float* __restrict__ kspart) {
    const int bh = blockIdx.x;          // 0..63
    const int s  = blockIdx.y;          // 0..15
    const int b  = bh >> 4;
    const int h  = bh & 15;
    const int t  = threadIdx.x;
    const int w  = t >> 6;              // wave 0..3
    const int lane = t & 63;
    const int rp = t >> 4;              // 0..15
    const int c4 = t & 15;

    // Two buffers of (Kp[32][68] + Vp[32][68]) h2 = 4352 floats each.
    __shared__ __align__(16) float pool[2 * 4352];
    __shared__ float ksred[4][64];

    const int dbase = (lane >> 3) * 8;
    const int mbase = (lane & 7) * 8;

    float acc[8][8] = {{0.f}};
    float ksum[8]   = {0.f};
    h2 one2; one2.x = (_Float16)1.0f; one2.y = (_Float16)1.0f;

    const float4* Kf4 = (const float4*)K;
    const float4* Vf4 = (const float4*)V;

    const int chunks = N_ / (S_ * 64);     // 4

    float4 kreg[4], vreg[4];

    // issue global loads for a chunk into registers
    auto LOAD = [&](int chunk) {
        const int n0 = s * (N_ / S_) + chunk * 64;
        size_t g = (size_t)(b * N_ + n0 + 2 * rp) * 256 + h * 16 + c4;
        kreg[0] = Kf4[g];             kreg[1] = Kf4[g + 256];
        kreg[2] = Kf4[g + 32 * 256];  kreg[3] = Kf4[g + 33 * 256];
        vreg[0] = Vf4[g];             vreg[1] = Vf4[g + 256];
        vreg[2] = Vf4[g + 32 * 256];  vreg[3] = Vf4[g + 33 * 256];
    };
    // convert + store registers into LDS buffer
    auto STORE = [&](int buf) {
        h2* Kp = (h2*)(pool + buf * 4352);
        h2* Vp = (h2*)(pool + buf * 4352 + 2176);
#pragma unroll
        for (int rep = 0; rep < 2; ++rep) {
            int rpx = rp + 16 * rep;
            float4 a = kreg[2 * rep], c = kreg[2 * rep + 1];
            H2x4 o;
            o.e[0] = phi2(a.x, c.x); o.e[1] = phi2(a.y, c.y);
            o.e[2] = phi2(a.z, c.z); o.e[3] = phi2(a.w, c.w);
            *(f4v*)&Kp[rpx * 68 + c4 * 4] = __builtin_bit_cast(f4v, o);
            a = vreg[2 * rep]; c = vreg[2 * rep + 1];
            H2x4 p;
            p.e[0].x = (_Float16)a.x; p.e[0].y = (_Float16)c.x;
            p.e[1].x = (_Float16)a.y; p.e[1].y = (_Float16)c.y;
            p.e[2].x = (_Float16)a.z; p.e[2].y = (_Float16)c.z;
            p.e[3].x = (_Float16)a.w; p.e[3].y = (_Float16)c.w;
            *(f4v*)&Vp[rpx * 68 + c4 * 4] = __builtin_bit_cast(f4v, p);
        }
    };

    LOAD(0);
    STORE(0);

    for (int chunk = 0; chunk < chunks; ++chunk) {
        if (chunk + 1 < chunks) LOAD(chunk + 1);   // in flight during compute
        __syncthreads();                           // buf[chunk&1] ready
        const int buf = chunk & 1;
        const h2* Kp = (const h2*)(pool + buf * 4352);
        const h2* Vp = (const h2*)(pool + buf * 4352 + 2176);
#pragma unroll
        for (int cc = 0; cc < 8; ++cc) {
            int c = w * 8 + cc;                 // n-pair index in chunk
            H2x4 kd0 = ld_h2x4(&Kp[c * 68 + dbase]);
            H2x4 kd1 = ld_h2x4(&Kp[c * 68 + dbase + 4]);
            H2x4 vm0 = ld_h2x4(&Vp[c * 68 + mbase]);
            H2x4 vm1 = ld_h2x4(&Vp[c * 68 + mbase + 4]);
            h2 kd[8] = {kd0.e[0], kd0.e[1], kd0.e[2], kd0.e[3],
                        kd1.e[0], kd1.e[1], kd1.e[2], kd1.e[3]};
            h2 vm[8] = {vm0.e[0], vm0.e[1], vm0.e[2], vm0.e[3],
                        vm1.e[0], vm1.e[1], vm1.e[2], vm1.e[3]};
#pragma unroll
            for (int i = 0; i < 8; ++i) {
#pragma unroll
                for (int j = 0; j < 8; ++j) acc[i][j] = fdot2(kd[i], vm[j], acc[i][j]);
                ksum[i] = fdot2(kd[i], one2, ksum[i]);
            }
        }
        if (chunk + 1 < chunks) STORE((chunk + 1) & 1);  // other buffer: safe
    }

    // ---- block-end reduction of 4 wave tiles ----
    if ((lane & 7) == 0) {
#pragma unroll
        for (int i = 0; i < 8; ++i) ksred[w][dbase + i] = ksum[i];
    }
    float* Red = pool;                   // 2 slots of 64*68 floats
    __syncthreads();

#define WRITE_T(slot)                                                          \
    {   float* T = Red + (slot) * 4352;                                        \
        _Pragma("unroll")                                                      \
        for (int i = 0; i < 8; ++i) {                                          \
            f4v o0 = {acc[i][0], acc[i][1], acc[i][2], acc[i][3]};             \
            f4v o1 = {acc[i][4], acc[i][5], acc[i][6], acc[i][7]};             \
            *(f4v*)&T[(dbase + i) * 68 + mbase]     = o0;                      \
            *(f4v*)&T[(dbase + i) * 68 + mbase + 4] = o1;                      \
        } }
#define ADD_T(slot)                                                            \
    {   float* T = Red + (slot) * 4352;                                        \
        _Pragma("unroll")                                                      \
        for (int i = 0; i < 8; ++i) {                                          \
            f4v r0 = *(f4v*)&T[(dbase + i) * 68 + mbase];                      \
            f4v r1 = *(f4v*)&T[(dbase + i) * 68 + mbase + 4];                  \
            acc[i][0] += r0[0]; acc[i][1] += r0[1];                            \
            acc[i][2] += r0[2]; acc[i][3] += r0[3];                            \
            acc[i][4] += r1[0]; acc[i][5] += r1[1];                            \
            acc[i][6] += r1[2]; acc[i][7] += r1[3];                            \
        } }

    if (w == 1) WRITE_T(0);
    if (w == 3) WRITE_T(1);
    __syncthreads();
    if (w == 0) ADD_T(0);
    if (w == 2) ADD_T(1);
    __syncthreads();
    if (w == 2) WRITE_T(0);
    __syncthreads();
    if (w == 0) {
        ADD_T(0);
        float4* kvp4 = (float4*)kvpart;
        const size_t base = (size_t)(bh * S_ + s) * 4096;
#pragma unroll
        for (int i = 0; i < 8; ++i) {
            float4 o0 = make_float4(acc[i][0], acc[i][1], acc[i][2], acc[i][3]);
            float4 o1 = make_float4(acc[i][4], acc[i][5], acc[i][6], acc[i][7]);
            kvp4[(base + (size_t)(dbase + i) * 64 + mbase) / 4]     = o0;
            kvp4[(base + (size_t)(dbase + i) * 64 + mbase + 4) / 4] = o1;
        }
        float ks = ksred[0][lane] + ksred[1][lane] + ksred[2][lane] + ksred[3][lane];
        kspart[(size_t)(bh * S_ + s) * 64 + lane] = ks;
    }
#undef WRITE_T
#undef ADD_T
}

// ---------------------------------------------------------------------------
// Kernel 1b: reduce partials -> KV, Ksum; M[d][j] = sum_m KV[d][m]*W[j][h*64+m]
// M stored d-pair-interleaved as half2 for the fdot2 consumer. grid 64, tiny.
// ---------------------------------------------------------------------------
__global__ __launch_bounds__(256) void k_makeM(const float* __restrict__ kvpart,
                                               const float* __restrict__ kspart,
                                               const float* __restrict__ W,
                                               float* __restrict__ Mh,
                                               float* __restrict__ Ksum) {
    const int bh = blockIdx.x;
    const int h  = bh & 15;
    const int t  = threadIdx.x;

    __shared__ float KVs[64][68];
    __shared__ float Ws[64][68];    // Ws[j][m]

    const float4* kv4 = (const float4*)kvpart;
    const float4* W4  = (const float4*)W;

    for (int idx = t; idx < 1024; idx += 256) {
        int row = idx >> 4, c4 = idx & 15;
        float4 r = make_float4(0.f, 0.f, 0.f, 0.f);
#pragma unroll 4
        for (int s = 0; s < S_; ++s) {
            float4 a = kv4[(size_t)(bh * S_ + s) * 1024 + idx];
            r.x += a.x; r.y += a.y; r.z += a.z; r.w += a.w;
        }
        *(float4*)&KVs[row][c4 * 4] = r;
        *(float4*)&Ws[row][c4 * 4] = W4[(size_t)row * 256 + h * 16 + c4];
    }
    if (t < 64) {
        float ks = 0.f;
        for (int s = 0; s < S_; ++s) ks += kspart[(size_t)(bh * S_ + s) * 64 + t];
        Ksum[(size_t)bh * 64 + t] = ks;
    }
    __syncthreads();

    const int dbase = (t >> 4) * 4, jbase = (t & 15) * 4;
    float acc[4][4] = {{0.f}};
#pragma unroll 4
    for (int m4 = 0; m4 < 16; ++m4) {
        float4 kvr[4], wr[4];
#pragma unroll
        for (int i = 0; i < 4; ++i) kvr[i] = *(const float4*)&KVs[dbase + i][m4 * 4];
#pragma unroll
        for (int j = 0; j < 4; ++j) wr[j] = *(const float4*)&Ws[jbase + j][m4 * 4];
#pragma unroll
        for (int i = 0; i < 4; ++i)
#pragma unroll
            for (int j = 0; j < 4; ++j)
                acc[i][j] += kvr[i].x * wr[j].x + kvr[i].y * wr[j].y +
                             kvr[i].z * wr[j].z + kvr[i].w * wr[j].w;
    }
    // Mh[bh][c][j] = half2{ M[2c][j], M[2c+1][j] },  c in [0,32), j in [0,64)
    f4v* M4 = (f4v*)Mh;
#pragma unroll
    for (int p = 0; p < 2; ++p) {
        int c = (dbase >> 1) + p;
        H2x4 o;
#pragma unroll
        for (int j = 0; j < 4; ++j) {
            o.e[j].x = (_Float16)acc[2 * p][j];
            o.e[j].y = (_Float16)acc[2 * p + 1][j];
        }
        M4[((size_t)bh * 2048 + c * 64 + jbase) / 4] = __builtin_bit_cast(f4v, o);
    }
}

// ---------------------------------------------------------------------------
// Kernel 2: outpart[hs][b,n,j] = sum_{h in slice} z_h(n) * phiQ_h[n,:] . M_h[:,j]
// grid (64 nc, 4 b, 4 hs) = 1024 blocks, 256 threads; 64 n-rows per block,
// 4n x 4j per thread. Head-pipelined: next head's Q/M/Ksum global loads are
// issued before the current head's compute; LDS double-buffered.
// ---------------------------------------------------------------------------
__global__ __launch_bounds__(256) void k_out(const float* __restrict__ Q,
                                             const float* __restrict__ Mh,
                                             const float* __restrict__ Ksum,
                                             float* __restrict__ outpart) {
    const int nc = blockIdx.x;     // 0..63
    const int b  = blockIdx.y;     // 0..3
    const int hs = blockIdx.z;     // 0..3
    const int n0 = nc * 64;
    const int t  = threadIdx.x;
    const int rp = t >> 4;         // 0..15
    const int c4 = t & 15;

    __shared__ __align__(16) h2 QpT[2][32 * 70];  // [c][n]: {phiQ[n][2c], phiQ[n][2c+1]}
    __shared__ __align__(16) h2 Msp[2][32 * 72];  // [c][j]: {M[2c][j], M[2c+1][j]}
    __shared__ h2 Kss[2][32];

    const int ibase = (t >> 4) * 4;   // n-row group
    const int jbase = (t & 15) * 4;   // j group
    float acc_out[4][4] = {{0.f}};

    const float4* Qf4 = (const float4*)Q;
    const f4v*    M4  = (const f4v*)Mh;

    float4 qr[4]; f4v mr[2]; float ksa = 0.f, ksb = 0.f;

    auto LOAD = [&](int hh) {
        const int h  = hs * 4 + hh;
        const int bh = b * 16 + h;
        size_t g = (size_t)(b * N_ + n0 + 2 * rp) * 256 + h * 16 + c4;
        qr[0] = Qf4[g];            qr[1] = Qf4[g + 256];
        qr[2] = Qf4[g + 32 * 256]; qr[3] = Qf4[g + 33 * 256];
        mr[0] = M4[(size_t)bh * 512 + t];
        mr[1] = M4[(size_t)bh * 512 + t + 256];
        if (t < 32) {
            ksa = Ksum[(size_t)bh * 64 + 2 * t];
            ksb = Ksum[(size_t)bh * 64 + 2 * t + 1];
        }
    };
    auto STOREH = [&](int buf) {
#pragma unroll
        for (int rep = 0; rep < 2; ++rep) {
            int rpx = rp + 16 * rep;                 // n-pair 0..31
            float4 a = qr[2 * rep], c = qr[2 * rep + 1];  // rows 2rpx, 2rpx+1
            st_h2x2(&QpT[buf][(2 * c4) * 70 + 2 * rpx],
                    phi2(a.x, a.y), phi2(c.x, c.y));
            st_h2x2(&QpT[buf][(2 * c4 + 1) * 70 + 2 * rpx],
                    phi2(a.z, a.w), phi2(c.z, c.w));
        }
        *(f4v*)&Msp[buf][(t >> 4) * 72 + (t & 15) * 4]        = mr[0];
        *(f4v*)&Msp[buf][((t >> 4) + 16) * 72 + (t & 15) * 4] = mr[1];
        if (t < 32) { h2 k; k.x = (_Float16)ksa; k.y = (_Float16)ksb; Kss[buf][t] = k; }
    };

    LOAD(0);
    STOREH(0);

    for (int hh = 0; hh < 4; ++hh) {
        if (hh + 1 < 4) LOAD(hh + 1);     // in flight during compute
        __syncthreads();
        const int buf = hh & 1;

        float sacc[4][4] = {{0.f}};
        float zacc[4]    = {0.f};
#pragma unroll 8
        for (int c = 0; c < 32; ++c) {
            H2x4 q = ld_h2x4(&QpT[buf][c * 70 + ibase]);
            H2x4 m = ld_h2x4(&Msp[buf][c * 72 + jbase]);
            h2 ks = Kss[buf][c];
#pragma unroll
            for (int i = 0; i < 4; ++i) {
                zacc[i] = fdot2(q.e[i], ks, zacc[i]);
#pragma unroll
                for (int j = 0; j < 4; ++j) sacc[i][j] = fdot2(q.e[i], m.e[j], sacc[i][j]);
            }
        }
#pragma unroll
        for (int i = 0; i < 4; ++i) {
            float z = 1.0f / (zacc[i] + EPS_);
#pragma unroll
            for (int j = 0; j < 4; ++j) acc_out[i][j] += z * sacc[i][j];
        }
        if (hh + 1 < 4) STOREH((hh + 1) & 1);   // other buffer: safe
    }

    float4* O4 = (float4*)outpart;
    const size_t slice = (size_t)hs * (B_ * N_ * 64);
#pragma unroll
    for (int i = 0; i < 4; ++i) {
        float4 o = make_float4(acc_out[i][0], acc_out[i][1], acc_out[i][2], acc_out[i][3]);
        O4[(slice + (size_t)(b * N_ + n0 + ibase + i) * 64 + jbase) / 4] = o;
    }
}

// ---------------------------------------------------------------------------
// Kernel 3: out = bias + sum_hs outpart[hs]
// ---------------------------------------------------------------------------
__global__ __launch_bounds__(256) void k_red(const float* __restrict__ outpart,
                                             const float* __restrict__ bout,
                                             float* __restrict__ out) {
    const int p = blockIdx.x * 256 + threadIdx.x;   // float4 index
    const float4* P4 = (const float4*)outpart;
    const float4* B4 = (const float4*)bout;
    float4 o = B4[p & 15];
    const int stride = B_ * N_ * 64 / 4;
#pragma unroll
    for (int hs = 0; hs < HS_; ++hs) {
        float4 a = P4[(size_t)hs * stride + p];
        o.x += a.x; o.y += a.y; o.z += a.z; o.w += a.w;
    }
    ((float4*)out)[p] = o;
}

// ---------------------------------------------------------------------------
extern "C" void kernel_launch(void* const* d_in, const int* in_sizes, int n_in,
                              void* d_out, int out_size, void* d_ws, size_t ws_size,
                              hipStream_t stream) {
    const float* q  = (const float*)d_in[0];
    const float* k  = (const float*)d_in[1];
    const float* v  = (const float*)d_in[2];
    const float* W  = (const float*)d_in[3];
    const float* bo = (const float*)d_in[4];
    float* out = (float*)d_out;

    float* ws      = (float*)d_ws;
    float* kvpart  = ws;                                    // 64*16*4096 = 4,194,304 f
    float* kspart  = kvpart + (size_t)BH_ * S_ * 4096;      // 64*16*64   = 65,536 f
    float* Mh      = kspart + (size_t)BH_ * S_ * 64;        // 64*2048 h2 = 131,072 f
    float* Ksum    = Mh + (size_t)BH_ * 2048;               // 64*64      = 4,096 f
    float* outpart = Ksum + (size_t)BH_ * 64;               // 4*1,048,576 f

    k_kvpart<<<dim3(BH_, S_), 256, 0, stream>>>(k, v, kvpart, kspart);
    k_makeM<<<BH_, 256, 0, stream>>>(kvpart, kspart, W, Mh, Ksum);
    k_out<<<dim3(N_ / 64, B_, HS_), 256, 0, stream>>>(q, Mh, Ksum, outpart);
    k_red<<<B_ * N_ * 64 / 4 / 256, 256, 0, stream>>>(outpart, bo, out);
}

// Round 5
// 228.267 us; speedup vs baseline: 1.1460x; 1.1460x over previous
//
#include <hip/hip_runtime.h>

#define B_  4
#define N_  4096
#define H_  16
#define BH_ 64
#define S_  16
#define HS_ 4
#define ST_ 72          // f16 stride of LDS tiles: 144 B rows (16B-aligned, even frag banks)
#define EPS_ 1e-6f

typedef _Float16 h2  __attribute__((ext_vector_type(2)));
typedef _Float16 h8  __attribute__((ext_vector_type(8)));
typedef float    f4v __attribute__((ext_vector_type(4)));

struct H2x2 { h2 a, b; };
struct H2x4 { h2 e[4]; };

__device__ __forceinline__ h8 ld_h8(const _Float16* p) {
    f4v r = *(const f4v*)p;                       // ds_read_b128
    return __builtin_bit_cast(h8, r);
}
__device__ __forceinline__ H2x4 ld_h2x4(const _Float16* p) {
    f4v r = *(const f4v*)p;
    return __builtin_bit_cast(H2x4, r);
}
__device__ __forceinline__ void st_h2x2(_Float16* p, h2 a, h2 b) {
    H2x2 t{a, b};
    *(float2*)p = __builtin_bit_cast(float2, t);  // ds_write_b64
}
__device__ __forceinline__ float phi(float x) {
    return x > 0.0f ? x + 1.0f : __expf(x);       // elu(x)+1
}
__device__ __forceinline__ float fdot2(h2 a, h2 b, float c) {
    return __builtin_amdgcn_fdot2(a, b, c, false);
}

// ---------------------------------------------------------------------------
// Kernel 1a: partial KV[d][m] = sum_n phi(K[n,d]) * V[n,m], partial Ksum.
// grid (64 bh, 16 s), 256 threads. MFMA 16x16x32_f16: 16 output tiles, 4 per
// wave (2 d-tiles x 2 m-tiles), full contraction per wave -> no cross-wave
// reduce. LDS stages transposed f16 tiles Kt[d][n], Vt[m][n]; reg-prefetch +
// double buffer.
// ---------------------------------------------------------------------------
__global__ __launch_bounds__(256) void k_kvpart(const float* __restrict__ K,
                                                const float* __restrict__ V,
                                                float* __restrict__ kvpart,
                                                float* __restrict__ kspart) {
    const int bh = blockIdx.x, s = blockIdx.y;
    const int b = bh >> 4, h = bh & 15;
    const int t = threadIdx.x, w = t >> 6, lane = t & 63;
    const int rp = t >> 4, c4 = t & 15;

    __shared__ __align__(16) _Float16 pool[2 * 2 * 64 * ST_];   // 36864 B
    __shared__ float ksred[4][64];

    const f4v* Kf4 = (const f4v*)K;
    const f4v* Vf4 = (const f4v*)V;

    f4v kreg[4], vreg[4];
    auto LOAD = [&](int chunk) {
        const int n0 = s * (N_ / S_) + chunk * 64;
        size_t g = (size_t)(b * N_ + n0 + 4 * rp) * 256 + h * 16 + c4;
        kreg[0] = Kf4[g];       kreg[1] = Kf4[g + 256];
        kreg[2] = Kf4[g + 512]; kreg[3] = Kf4[g + 768];
        vreg[0] = Vf4[g];       vreg[1] = Vf4[g + 256];
        vreg[2] = Vf4[g + 512]; vreg[3] = Vf4[g + 768];
    };
    auto STORE = [&](int buf) {
        _Float16* Kt = pool + buf * (2 * 64 * ST_);
        _Float16* Vt = Kt + 64 * ST_;
#pragma unroll
        for (int dj = 0; dj < 4; ++dj) {
            int d = 4 * c4 + dj;
            h2 lo, hi;
            lo.x = (_Float16)phi(kreg[0][dj]); lo.y = (_Float16)phi(kreg[1][dj]);
            hi.x = (_Float16)phi(kreg[2][dj]); hi.y = (_Float16)phi(kreg[3][dj]);
            st_h2x2(&Kt[d * ST_ + 4 * rp], lo, hi);
            lo.x = (_Float16)vreg[0][dj]; lo.y = (_Float16)vreg[1][dj];
            hi.x = (_Float16)vreg[2][dj]; hi.y = (_Float16)vreg[3][dj];
            st_h2x2(&Vt[d * ST_ + 4 * rp], lo, hi);
        }
    };

    const int td0 = 2 * (w >> 1);     // d-tile pair base (tiles of 16)
    const int tj0 = 2 * (w & 1);      // m-tile pair base
    const int rA  = lane & 15;
    const int fo  = (lane >> 4) * 8;  // k-offset within a 32-step

    f4v acc[2][2];
#pragma unroll
    for (int a = 0; a < 2; ++a)
#pragma unroll
        for (int bb = 0; bb < 2; ++bb) acc[a][bb] = (f4v){0.f, 0.f, 0.f, 0.f};
    float ksum_acc = 0.f;
    h2 one2; one2.x = (_Float16)1.0f; one2.y = (_Float16)1.0f;

    LOAD(0);
    STORE(0);

    for (int chunk = 0; chunk < 4; ++chunk) {
        if (chunk + 1 < 4) LOAD(chunk + 1);
        __syncthreads();
        const int buf = chunk & 1;
        const _Float16* Kt = pool + buf * (2 * 64 * ST_);
        const _Float16* Vt = Kt + 64 * ST_;
#pragma unroll
        for (int ks = 0; ks < 2; ++ks) {
            h8 a0 = ld_h8(&Kt[(16 * (td0 + 0) + rA) * ST_ + ks * 32 + fo]);
            h8 a1 = ld_h8(&Kt[(16 * (td0 + 1) + rA) * ST_ + ks * 32 + fo]);
            h8 b0 = ld_h8(&Vt[(16 * (tj0 + 0) + rA) * ST_ + ks * 32 + fo]);
            h8 b1 = ld_h8(&Vt[(16 * (tj0 + 1) + rA) * ST_ + ks * 32 + fo]);
            acc[0][0] = __builtin_amdgcn_mfma_f32_16x16x32_f16(a0, b0, acc[0][0], 0, 0, 0);
            acc[0][1] = __builtin_amdgcn_mfma_f32_16x16x32_f16(a0, b1, acc[0][1], 0, 0, 0);
            acc[1][0] = __builtin_amdgcn_mfma_f32_16x16x32_f16(a1, b0, acc[1][0], 0, 0, 0);
            acc[1][1] = __builtin_amdgcn_mfma_f32_16x16x32_f16(a1, b1, acc[1][1], 0, 0, 0);
        }
        // Ksum quarter-partials: thread t handles d = lane-ish, n-quarter = w
        {
            int d = t & 63, qtr = t >> 6;
            H2x4 x0 = ld_h2x4(&Kt[d * ST_ + qtr * 16]);
            H2x4 x1 = ld_h2x4(&Kt[d * ST_ + qtr * 16 + 8]);
#pragma unroll
            for (int i = 0; i < 4; ++i) {
                ksum_acc = fdot2(x0.e[i], one2, ksum_acc);
                ksum_acc = fdot2(x1.e[i], one2, ksum_acc);
            }
        }
        if (chunk + 1 < 4) STORE((chunk + 1) & 1);
    }

    // epilogue: direct store of the wave's 4 tiles (C layout: col=lane&15,
    // row=(lane>>4)*4+reg — HW-verified m89)
    float* outp = kvpart + (size_t)(bh * S_ + s) * 4096;
#pragma unroll
    for (int a = 0; a < 2; ++a)
#pragma unroll
        for (int bb = 0; bb < 2; ++bb)
#pragma unroll
            for (int r = 0; r < 4; ++r) {
                int d = 16 * (td0 + a) + (lane >> 4) * 4 + r;
                int m = 16 * (tj0 + bb) + (lane & 15);
                outp[d * 64 + m] = acc[a][bb][r];
            }
    ksred[t >> 6][t & 63] = ksum_acc;
    __syncthreads();
    if (t < 64) {
        kspart[(size_t)(bh * S_ + s) * 64 + t] =
            ksred[0][t] + ksred[1][t] + ksred[2][t] + ksred[3][t];
    }
}

// ---------------------------------------------------------------------------
// Kernel 1b: reduce partials -> KV, Ksum; Mt[j][d] = sum_m KV[d][m]*W[j][h*64+m]
// output TRANSPOSED f16 (row j, contiguous d) for k_out's B-fragment reads.
// ---------------------------------------------------------------------------
__global__ __launch_bounds__(256) void k_makeM(const float* __restrict__ kvpart,
                                               const float* __restrict__ kspart,
                                               const float* __restrict__ W,
                                               _Float16* __restrict__ Mt,
                                               float* __restrict__ Ksum) {
    const int bh = blockIdx.x;
    const int h  = bh & 15;
    const int t  = threadIdx.x;

    __shared__ float KVs[64][68];
    __shared__ float Ws[64][68];    // Ws[j][m]

    const f4v* kv4 = (const f4v*)kvpart;
    const f4v* W4  = (const f4v*)W;

    for (int idx = t; idx < 1024; idx += 256) {
        int row = idx >> 4, c4 = idx & 15;
        f4v r = {0.f, 0.f, 0.f, 0.f};
#pragma unroll 4
        for (int s = 0; s < S_; ++s) {
            f4v a = kv4[(size_t)(bh * S_ + s) * 1024 + idx];
            r += a;
        }
        *(f4v*)&KVs[row][c4 * 4] = r;
        *(f4v*)&Ws[row][c4 * 4] = W4[(size_t)row * 256 + h * 16 + c4];
    }
    if (t < 64) {
        float ks = 0.f;
        for (int s = 0; s < S_; ++s) ks += kspart[(size_t)(bh * S_ + s) * 64 + t];
        Ksum[(size_t)bh * 64 + t] = ks;
    }
    __syncthreads();

    const int jbase = (t >> 4) * 4, dbase = (t & 15) * 4;
    float acc[4][4] = {{0.f}};      // [jj][dd]
#pragma unroll 4
    for (int m4 = 0; m4 < 16; ++m4) {
        f4v wr[4], kvr[4];
#pragma unroll
        for (int j = 0; j < 4; ++j) wr[j] = *(const f4v*)&Ws[jbase + j][m4 * 4];
#pragma unroll
        for (int i = 0; i < 4; ++i) kvr[i] = *(const f4v*)&KVs[dbase + i][m4 * 4];
#pragma unroll
        for (int j = 0; j < 4; ++j)
#pragma unroll
            for (int i = 0; i < 4; ++i)
                acc[j][i] += wr[j][0] * kvr[i][0] + wr[j][1] * kvr[i][1] +
                             wr[j][2] * kvr[i][2] + wr[j][3] * kvr[i][3];
    }
#pragma unroll
    for (int j = 0; j < 4; ++j) {
        h2 lo, hi;
        lo.x = (_Float16)acc[j][0]; lo.y = (_Float16)acc[j][1];
        hi.x = (_Float16)acc[j][2]; hi.y = (_Float16)acc[j][3];
        H2x2 pk{lo, hi};
        *(float2*)&Mt[((size_t)bh * 64 + jbase + j) * 64 + dbase] =
            __builtin_bit_cast(float2, pk);
    }
}

// ---------------------------------------------------------------------------
// Kernel 2: outpart[hs][b,n,j] = sum_{h in slice} z_h(n) * phiQ_h[n,:] . M_h[:,j]
// grid (64 nc, 4 b, 4 hs), 256 threads; 64 n-rows/block, 4 heads/block.
// MFMA: A = phiQ[n][d] (row-major, no transpose), B = Mt[j][d].
// ---------------------------------------------------------------------------
__global__ __launch_bounds__(256) void k_out(const float* __restrict__ Q,
                                             const _Float16* __restrict__ Mtg,
                                             const float* __restrict__ Ksum,
                                             float* __restrict__ outpart) {
    const int nc = blockIdx.x, b = blockIdx.y, hs = blockIdx.z;
    const int n0 = nc * 64;
    const int t = threadIdx.x, w = t >> 6, lane = t & 63;
    const int rp4 = t >> 4, c4 = t & 15;

    __shared__ __align__(16) _Float16 pool[2 * 2 * 64 * ST_];   // Qp + Mt per buf
    __shared__ float zz[64];
    __shared__ h2 Kss[2][32];

    const f4v* Qf4 = (const f4v*)Q;

    f4v qr[4], mr[2];
    float ksa = 0.f, ksb = 0.f;
    auto LOAD = [&](int hh) {
        const int h = hs * 4 + hh, bh = b * 16 + h;
        size_t g = (size_t)(b * N_ + n0 + rp4) * 256 + h * 16 + c4;
        qr[0] = Qf4[g];            qr[1] = Qf4[g + 16 * 256];
        qr[2] = Qf4[g + 32 * 256]; qr[3] = Qf4[g + 48 * 256];
        mr[0] = ((const f4v*)Mtg)[(size_t)bh * 512 + t];
        mr[1] = ((const f4v*)Mtg)[(size_t)bh * 512 + t + 256];
        if (t < 32) {
            ksa = Ksum[(size_t)bh * 64 + 2 * t];
            ksb = Ksum[(size_t)bh * 64 + 2 * t + 1];
        }
    };
    auto STORE = [&](int buf) {
        _Float16* Qp = pool + buf * (2 * 64 * ST_);
        _Float16* Mt = Qp + 64 * ST_;
#pragma unroll
        for (int r = 0; r < 4; ++r) {
            int row = rp4 + 16 * r;
            h2 p0, p1;
            p0.x = (_Float16)phi(qr[r][0]); p0.y = (_Float16)phi(qr[r][1]);
            p1.x = (_Float16)phi(qr[r][2]); p1.y = (_Float16)phi(qr[r][3]);
            st_h2x2(&Qp[row * ST_ + 4 * c4], p0, p1);
        }
        *(f4v*)&Mt[(t >> 3) * ST_ + (t & 7) * 8] = mr[0];
        *(f4v*)&Mt[((t + 256) >> 3) * ST_ + (t & 7) * 8] = mr[1];
        if (t < 32) { h2 kk; kk.x = (_Float16)ksa; kk.y = (_Float16)ksb; Kss[buf][t] = kk; }
    };

    const int tn0 = 2 * (w >> 1), tj0 = 2 * (w & 1);
    const int rA = lane & 15, fo = (lane >> 4) * 8;
    float facc[2][2][4] = {{{0.f}}};

    LOAD(0);
    STORE(0);

    for (int hh = 0; hh < 4; ++hh) {
        if (hh + 1 < 4) LOAD(hh + 1);
        __syncthreads();
        const int buf = hh & 1;
        const _Float16* Qp = pool + buf * (2 * 64 * ST_);
        const _Float16* Mt = Qp + 64 * ST_;

        if (t < 64) {            // z-denominator for row t
            float zp = 0.f;
#pragma unroll
            for (int c = 0; c < 8; ++c) {
                H2x4 x = ld_h2x4(&Qp[t * ST_ + c * 8]);
#pragma unroll
                for (int i = 0; i < 4; ++i) zp = fdot2(x.e[i], Kss[buf][c * 4 + i], zp);
            }
            zz[t] = 1.0f / (zp + EPS_);
        }
        __syncthreads();

        f4v acc[2][2];
#pragma unroll
        for (int a = 0; a < 2; ++a)
#pragma unroll
            for (int bb = 0; bb < 2; ++bb) acc[a][bb] = (f4v){0.f, 0.f, 0.f, 0.f};
#pragma unroll
        for (int ks = 0; ks < 2; ++ks) {
            h8 a0 = ld_h8(&Qp[(16 * (tn0 + 0) + rA) * ST_ + ks * 32 + fo]);
            h8 a1 = ld_h8(&Qp[(16 * (tn0 + 1) + rA) * ST_ + ks * 32 + fo]);
            h8 b0 = ld_h8(&Mt[(16 * (tj0 + 0) + rA) * ST_ + ks * 32 + fo]);
            h8 b1 = ld_h8(&Mt[(16 * (tj0 + 1) + rA) * ST_ + ks * 32 + fo]);
            acc[0][0] = __builtin_amdgcn_mfma_f32_16x16x32_f16(a0, b0, acc[0][0], 0, 0, 0);
            acc[0][1] = __builtin_amdgcn_mfma_f32_16x16x32_f16(a0, b1, acc[0][1], 0, 0, 0);
            acc[1][0] = __builtin_amdgcn_mfma_f32_16x16x32_f16(a1, b0, acc[1][0], 0, 0, 0);
            acc[1][1] = __builtin_amdgcn_mfma_f32_16x16x32_f16(a1, b1, acc[1][1], 0, 0, 0);
        }
#pragma unroll
        for (int a = 0; a < 2; ++a)
#pragma unroll
            for (int r = 0; r < 4; ++r) {
                int row = 16 * (tn0 + a) + (lane >> 4) * 4 + r;
                float z = zz[row];
                facc[a][0][r] += z * acc[a][0][r];
                facc[a][1][r] += z * acc[a][1][r];
            }
        if (hh + 1 < 4) STORE((hh + 1) & 1);
    }

    float* op = outpart + (size_t)hs * (B_ * N_ * 64);
#pragma unroll
    for (int a = 0; a < 2; ++a)
#pragma unroll
        for (int bb = 0; bb < 2; ++bb)
#pragma unroll
            for (int r = 0; r < 4; ++r) {
                int n = 16 * (tn0 + a) + (lane >> 4) * 4 + r;
                int j = 16 * (tj0 + bb) + (lane & 15);
                op[(size_t)(b * N_ + n0 + n) * 64 + j] = facc[a][bb][r];
            }
}

// ---------------------------------------------------------------------------
// Kernel 3: out = bias + sum_hs outpart[hs]
// ---------------------------------------------------------------------------
__global__ __launch_bounds__(256) void k_red(const float* __restrict__ outpart,
                                             const float* __restrict__ bout,
                                             float* __restrict__ out) {
    const int p = blockIdx.x * 256 + threadIdx.x;
    const f4v* P4 = (const f4v*)outpart;
    const f4v* B4 = (const f4v*)bout;
    f4v o = B4[p & 15];
    const int stride = B_ * N_ * 64 / 4;
#pragma unroll
    for (int hs = 0; hs < HS_; ++hs) o += P4[(size_t)hs * stride + p];
    ((f4v*)out)[p] = o;
}

// ---------------------------------------------------------------------------
extern "C" void kernel_launch(void* const* d_in, const int* in_sizes, int n_in,
                              void* d_out, int out_size, void* d_ws, size_t ws_size,
                              hipStream_t stream) {
    const float* q  = (const float*)d_in[0];
    const float* k  = (const float*)d_in[1];
    const float* v  = (const float*)d_in[2];
    const float* W  = (const float*)d_in[3];
    const float* bo = (const float*)d_in[4];
    float* out = (float*)d_out;

    float* ws      = (float*)d_ws;
    float* kvpart  = ws;                                    // 64*16*4096 = 16 MB
    float* kspart  = kvpart + (size_t)BH_ * S_ * 4096;      // 256 KB
    float* Mt      = kspart + (size_t)BH_ * S_ * 64;        // 64*4096 f16 = 512 KB
    float* Ksum    = Mt + (size_t)BH_ * 4096 / 2;           // 16 KB
    float* outpart = Ksum + (size_t)BH_ * 64;               // 4 * 4 MB

    k_kvpart<<<dim3(BH_, S_), 256, 0, stream>>>(k, v, kvpart, kspart);
    k_makeM<<<BH_, 256, 0, stream>>>(kvpart, kspart, W, (_Float16*)Mt, Ksum);
    k_out<<<dim3(N_ / 64, B_, HS_), 256, 0, stream>>>(q, (const _Float16*)Mt, Ksum, outpart);
    k_red<<<B_ * N_ * 64 / 4 / 256, 256, 0, stream>>>(outpart, bo, out);
}